// Round 6
// baseline (2054.964 us; speedup 1.0000x reference)
//
#include <hip/hip_runtime.h>

// Problem dims
#define BDIM 32
#define NDIM 400
#define TDIM 315
#define TPAD 320
#define DDIM 512
#define HDIM 256
#define NITER 100

// Workspace layout (bytes)
#define OFS_TA    0u          // tA[320][512] f32 = 655360
#define OFS_TB    1048576u    // TB[320][256] f32 = 327680   (text @ Wh_bot + bh)
#define OFS_STATS 1572864u    // stats[32][2] f32 = 256      (sum, sumsq per batch)
#define OFS_S     2097152u    // s/s1[32][400][320] f32 = 16384000
#define OFS_F1    18874368u   // f1[32][315][512] f32 = 20643840
#define OFS_H     41943040u   // h[10080][256] f32 = 10321920

// ---------------- shared GEMM pieces: 64x64 tile, BK=32, 256 thr, 4x4 micro ----------------

__device__ __forceinline__ void mm_inner(const float* __restrict__ As, const float* __restrict__ Bs,
                                         float acc[4][4], int tm, int tn) {
#pragma unroll
  for (int k = 0; k < 32; ++k) {
    float4 a = *(const float4*)(As + k * 72 + tm * 4);
    float4 b = *(const float4*)(Bs + k * 72 + tn * 4);
    float ar[4] = {a.x, a.y, a.z, a.w};
    float br[4] = {b.x, b.y, b.z, b.w};
#pragma unroll
    for (int i = 0; i < 4; ++i)
#pragma unroll
      for (int j = 0; j < 4; ++j)
        acc[i][j] = fmaf(ar[i], br[j], acc[i][j]);
  }
}

// Stage X[row][k] (K-contiguous rows) transposed into Xs[k][m]; rows >= rmax -> 0
__device__ __forceinline__ void stage_T(float* __restrict__ Xs, const float* __restrict__ X,
                                        int r0, int ld, int k0, int tid, int rmax) {
  int kq = tid & 7;   // float4 group along K
  int mb = tid >> 3;  // 0..31
#pragma unroll
  for (int p = 0; p < 2; ++p) {
    int mm = mb + 32 * p;
    int row = r0 + mm;
    float4 v = make_float4(0.f, 0.f, 0.f, 0.f);
    if (row < rmax) v = *(const float4*)(X + (size_t)row * ld + k0 + 4 * kq);
    Xs[(4 * kq + 0) * 72 + mm] = v.x;
    Xs[(4 * kq + 1) * 72 + mm] = v.y;
    Xs[(4 * kq + 2) * 72 + mm] = v.z;
    Xs[(4 * kq + 3) * 72 + mm] = v.w;
  }
}

// Stage W[k][n] (N-contiguous rows) into Ws[k][j]; k0+k >= kmax -> 0
__device__ __forceinline__ void stage_N(float* __restrict__ Ws, const float* __restrict__ W,
                                        int k0, int ld, int n0, int tid, int kmax) {
  int nq = tid & 15;
  int kk = tid >> 4;  // 0..15
#pragma unroll
  for (int p = 0; p < 2; ++p) {
    int k = kk + 16 * p;
    float4 v = make_float4(0.f, 0.f, 0.f, 0.f);
    if (k0 + k < kmax) v = *(const float4*)(W + (size_t)(k0 + k) * ld + n0 + 4 * nq);
    *(float4*)(Ws + k * 72 + 4 * nq) = v;
  }
}

// ---------------- K1a: tA[t][d] = sum_e text[t][e] * A[d][e]  (NT) ----------------
__global__ void k_tA(const float* __restrict__ text, const float* __restrict__ A,
                     float* __restrict__ tA) {
  __shared__ float Xs[32 * 72], Ys[32 * 72];
  int tid = threadIdx.x, tm = tid >> 4, tn = tid & 15;
  int d0 = blockIdx.x * 64, t0 = blockIdx.y * 64;
  float acc[4][4] = {};
  for (int k0 = 0; k0 < 512; k0 += 32) {
    stage_T(Xs, text, t0, 512, k0, tid, TDIM);
    stage_T(Ys, A, d0, 512, k0, tid, 512);
    __syncthreads();
    mm_inner(Xs, Ys, acc, tm, tn);
    __syncthreads();
  }
#pragma unroll
  for (int i = 0; i < 4; ++i) {
    int t = t0 + tm * 4 + i;  // pad rows get zeros (Xs zero-filled)
    *(float4*)(tA + (size_t)t * 512 + d0 + tn * 4) =
        make_float4(acc[i][0], acc[i][1], acc[i][2], acc[i][3]);
  }
}

// ---------------- K1b: TB[t][h] = text[t]. @ Wh_bot + bh  (NN) ----------------
__global__ void k_TB(const float* __restrict__ text, const float* __restrict__ Wh,
                     const float* __restrict__ bh, float* __restrict__ TB) {
  __shared__ float Xs[32 * 72], Ws[32 * 72];
  int tid = threadIdx.x, tm = tid >> 4, tn = tid & 15;
  int h0 = blockIdx.x * 64, t0 = blockIdx.y * 64;
  const float* Wb = Wh + 512 * 256;  // bottom half rows of Wh[1024][256]
  float acc[4][4] = {};
  for (int k0 = 0; k0 < 512; k0 += 32) {
    stage_T(Xs, text, t0, 512, k0, tid, TDIM);
    stage_N(Ws, Wb, k0, 256, h0, tid, 512);
    __syncthreads();
    mm_inner(Xs, Ws, acc, tm, tn);
    __syncthreads();
  }
#pragma unroll
  for (int i = 0; i < 4; ++i) {
    int t = t0 + tm * 4 + i;
    int h = h0 + tn * 4;
    *(float4*)(TB + (size_t)t * 256 + h) =
        make_float4(acc[i][0] + bh[h], acc[i][1] + bh[h + 1],
                    acc[i][2] + bh[h + 2], acc[i][3] + bh[h + 3]);
  }
}

// ---------------- K2: s[b][n][t] = F[b][n]. dot tA[t].  (NT) + instnorm stats ----------------
__global__ void k_s(const float* __restrict__ F, const float* __restrict__ tA,
                    float* __restrict__ s, float* __restrict__ stats) {
  __shared__ float Xs[32 * 72], Ys[32 * 72];
  __shared__ float red[8];
  int tid = threadIdx.x, tm = tid >> 4, tn = tid & 15;
  int t0 = blockIdx.x * 64, n0 = blockIdx.y * 64, bz = blockIdx.z;
  const float* Fb = F + (size_t)bz * NDIM * DDIM;
  float* sb = s + (size_t)bz * NDIM * TPAD;
  float acc[4][4] = {};
  for (int k0 = 0; k0 < 512; k0 += 32) {
    stage_T(Xs, Fb, n0, 512, k0, tid, NDIM);
    stage_T(Ys, tA, t0, 512, k0, tid, TPAD);  // pad rows of tA are zeros
    __syncthreads();
    mm_inner(Xs, Ys, acc, tm, tn);
    __syncthreads();
  }
  float lsum = 0.f, lsq = 0.f;
#pragma unroll
  for (int i = 0; i < 4; ++i) {
    int n = n0 + tm * 4 + i;
    if (n < NDIM) {
      int tb = t0 + tn * 4;
      if (tb + 3 < TDIM) {
        *(float4*)(sb + (size_t)n * TPAD + tb) =
            make_float4(acc[i][0], acc[i][1], acc[i][2], acc[i][3]);
#pragma unroll
        for (int j = 0; j < 4; ++j) { lsum += acc[i][j]; lsq = fmaf(acc[i][j], acc[i][j], lsq); }
      } else {
#pragma unroll
        for (int j = 0; j < 4; ++j) {
          int t = tb + j;
          if (t < TDIM) {
            sb[(size_t)n * TPAD + t] = acc[i][j];
            lsum += acc[i][j]; lsq = fmaf(acc[i][j], acc[i][j], lsq);
          }
        }
      }
    }
  }
#pragma unroll
  for (int m = 1; m <= 32; m <<= 1) {
    lsum += __shfl_xor(lsum, m, 64);
    lsq  += __shfl_xor(lsq, m, 64);
  }
  int wv = tid >> 6;
  if ((tid & 63) == 0) { red[wv * 2] = lsum; red[wv * 2 + 1] = lsq; }
  __syncthreads();
  if (tid == 0) {
    float S = red[0] + red[2] + red[4] + red[6];
    float Q = red[1] + red[3] + red[5] + red[7];
    atomicAdd(&stats[bz * 2], S);
    atomicAdd(&stats[bz * 2 + 1], Q);
  }
}

// ---------------- DPP wave-64 sum helpers (VALU pipe, no LDS) ----------------
template <int CTRL, int RMASK>
__device__ __forceinline__ float dppadd(float x) {
  int y = __builtin_amdgcn_update_dpp(0, __float_as_int(x), CTRL, RMASK, 0xf, true);
  return x + __int_as_float(y);
}

// ---------------- bf16 pack/unpack (RNE) ----------------
__device__ __forceinline__ unsigned rne_hi(float x) {
  unsigned u = __float_as_uint(x);
  u += 0x7fffu + ((u >> 16) & 1u);
  return u & 0xffff0000u;
}
__device__ __forceinline__ unsigned pack2(float lo, float hi) {
  return (rne_hi(lo) >> 16) | rne_hi(hi);
}
__device__ __forceinline__ float unpk_lo(unsigned p) { return __uint_as_float(p << 16); }
__device__ __forceinline__ float unpk_hi(unsigned p) { return __uint_as_float(p & 0xffff0000u); }

// ---------------- K3: fused instnorm finalize + 100-iter sinkhorn (matrix scaling) ----------------
// 512 threads (8 waves). R2-R5 measured: the compiler pins the VGPR budget at 2 blocks/CU worth of
// waves (512thr -> 128 VGPRs) and ignores __launch_bounds__ 2nd arg / amdgpu_waves_per_eu. So make
// demand FIT 128: E stripes 0-3 stored as packed bf16 pairs (E01[50],E23[50] = 100 VGPRs; unpack =
// 1 VALU op per use; all math fp32), stripe 4 fp32 in LDS. Peak live ~125 -> zero spill.
// aj scalars live in SGPRs (readlane); e4 re-read from LDS in the q-phase (not kept live).
// Iterate a = 1/(E w), w = 1/(E^T a); output s1 = a_100 * E * w_100 with a_100 saved in the peeled
// LAST iteration only — reference ends on a COL normalization; recomputing a would add a row norm.
__global__ __launch_bounds__(512) void k_sinkhorn(float* __restrict__ sbuf,
                                                  const float* __restrict__ stats,
                                                  const float* __restrict__ gptr,
                                                  const float* __restrict__ bptr) {
  __shared__ float Elds[400 * 64];   // stripe k=4 (t = 256+l), fp32, zero for l>=59
  __shared__ float wl[320];          // col scaling w[t] (0 for t>=315)
  __shared__ float qacc[8 * 320];    // per-wave col partials
  __shared__ float albuf[400];       // row scaling a[n] from the final row step
  const int b = blockIdx.x;
  const int tid = threadIdx.x;
  const int wv = tid >> 6;           // 0..7
  const int l = tid & 63;
  float* S = sbuf + (size_t)b * NDIM * TPAD;
  const float NT = 400.0f * 315.0f;
  const float mean = stats[2 * b] / NT;
  const float var = stats[2 * b + 1] / NT - mean * mean;
  const float inv = rsqrtf(var + 1e-5f);
  const float gamma = gptr[0], beta = bptr[0];
  const float alpha = gamma * inv;
  const float L2E = 1.4426950408889634f;
  const float a2 = alpha * L2E;
  const float d2 = (beta - mean * alpha) * L2E;
  const int nbase = wv * 50;         // 50 rows per wave

  unsigned E01[50], E23[50];         // packed bf16: (stripe0,stripe1), (stripe2,stripe3)
#pragma unroll
  for (int j = 0; j < 50; ++j) {
    const float* row = S + (size_t)(nbase + j) * TPAD;
    float e0 = __builtin_amdgcn_exp2f(fmaf(row[l], a2, d2));
    float e1 = __builtin_amdgcn_exp2f(fmaf(row[64 + l], a2, d2));
    float e2 = __builtin_amdgcn_exp2f(fmaf(row[128 + l], a2, d2));
    float e3 = __builtin_amdgcn_exp2f(fmaf(row[192 + l], a2, d2));
    E01[j] = pack2(e0, e1);
    E23[j] = pack2(e2, e3);
    float e4 = 0.0f;
    if (l < 59) e4 = __builtin_amdgcn_exp2f(fmaf(row[256 + l], a2, d2));
    Elds[(nbase + j) * 64 + l] = e4;
  }
  if (tid < 320) wl[tid] = (tid < 315) ? 1.0f : 0.0f;
  __syncthreads();

  for (int it = 0; it < NITER; ++it) {
    const bool last = (it == NITER - 1);
    float w0 = wl[l], w1 = wl[64 + l], w2 = wl[128 + l], w3 = wl[192 + l], w4 = wl[256 + l];
    float q0 = 0.f, q1 = 0.f, q2 = 0.f, q3 = 0.f, q4 = 0.f;
#pragma unroll
    for (int jc = 0; jc < 10; ++jc) {
      float p[5];
#pragma unroll
      for (int u = 0; u < 5; ++u) {
        const int j = jc * 5 + u;
        float t = Elds[(nbase + j) * 64 + l] * w4;
        t = fmaf(unpk_hi(E23[j]), w3, t);
        t = fmaf(unpk_lo(E23[j]), w2, t);
        t = fmaf(unpk_hi(E01[j]), w1, t);
        p[u] = fmaf(unpk_lo(E01[j]), w0, t);
      }
      // 5 interleaved DPP reduction chains (ILP), results uniform in SGPRs
      float aj[5];
#pragma unroll
      for (int u = 0; u < 5; ++u) p[u] = dppadd<0x111, 0xf>(p[u]);
#pragma unroll
      for (int u = 0; u < 5; ++u) p[u] = dppadd<0x112, 0xf>(p[u]);
#pragma unroll
      for (int u = 0; u < 5; ++u) p[u] = dppadd<0x114, 0xf>(p[u]);
#pragma unroll
      for (int u = 0; u < 5; ++u) p[u] = dppadd<0x118, 0xf>(p[u]);
#pragma unroll
      for (int u = 0; u < 5; ++u) p[u] = dppadd<0x142, 0xa>(p[u]);
#pragma unroll
      for (int u = 0; u < 5; ++u) p[u] = dppadd<0x143, 0xc>(p[u]);
#pragma unroll
      for (int u = 0; u < 5; ++u) {
        float r = __builtin_amdgcn_rcpf(p[u]);
        aj[u] = __int_as_float(__builtin_amdgcn_readlane(__float_as_int(r), 63));
      }
#pragma unroll
      for (int u = 0; u < 5; ++u) {
        const int j = jc * 5 + u;
        q0 = fmaf(unpk_lo(E01[j]), aj[u], q0);
        q1 = fmaf(unpk_hi(E01[j]), aj[u], q1);
        q2 = fmaf(unpk_lo(E23[j]), aj[u], q2);
        q3 = fmaf(unpk_hi(E23[j]), aj[u], q3);
        q4 = fmaf(Elds[(nbase + j) * 64 + l], aj[u], q4);
      }
      if (last && l == 0) {
#pragma unroll
        for (int u = 0; u < 5; ++u) albuf[nbase + jc * 5 + u] = aj[u];
      }
    }
    qacc[wv * 320 + l] = q0;
    qacc[wv * 320 + 64 + l] = q1;
    qacc[wv * 320 + 128 + l] = q2;
    qacc[wv * 320 + 192 + l] = q3;
    qacc[wv * 320 + 256 + l] = q4;
    __syncthreads();
    if (tid < 320) {
      float q = 0.f;
#pragma unroll
      for (int ww = 0; ww < 8; ++ww) q += qacc[ww * 320 + tid];
      wl[tid] = (tid < 315) ? __builtin_amdgcn_rcpf(q) : 0.0f;
    }
    __syncthreads();
  }

  // epilogue: s1 = a_100 * E * w_100 (a from albuf — NO extra row normalization)
  {
    float w0 = wl[l], w1 = wl[64 + l], w2 = wl[128 + l], w3 = wl[192 + l], w4 = wl[256 + l];
#pragma unroll
    for (int j = 0; j < 50; ++j) {
      const float aj = albuf[nbase + j];
      const float e4 = Elds[(nbase + j) * 64 + l];
      float* row = S + (size_t)(nbase + j) * TPAD;
      row[l] = aj * unpk_lo(E01[j]) * w0;
      row[64 + l] = aj * unpk_hi(E01[j]) * w1;
      row[128 + l] = aj * unpk_lo(E23[j]) * w2;
      row[192 + l] = aj * unpk_hi(E23[j]) * w3;
      if (l < 59) row[256 + l] = aj * e4 * w4;
    }
  }
}

// ---------------- K4: f1[b][t][d] = sum_n s1[b][n][t] * F[b][n][d]  (TN) ----------------
__global__ void k_f1(const float* __restrict__ s1, const float* __restrict__ F,
                     float* __restrict__ f1) {
  __shared__ float Xs[32 * 72], Ws[32 * 72];
  int tid = threadIdx.x, tm = tid >> 4, tn = tid & 15;
  int d0 = blockIdx.x * 64, t0 = blockIdx.y * 64, bz = blockIdx.z;
  const float* sb = s1 + (size_t)bz * NDIM * TPAD;
  const float* Fb = F + (size_t)bz * NDIM * DDIM;
  float* out = f1 + (size_t)bz * TDIM * DDIM;
  float acc[4][4] = {};
  for (int k0 = 0; k0 < 416; k0 += 32) {  // 13 chunks cover K=400 (masked)
    stage_N(Xs, sb, k0, TPAD, t0, tid, NDIM);
    stage_N(Ws, Fb, k0, DDIM, d0, tid, NDIM);
    __syncthreads();
    mm_inner(Xs, Ws, acc, tm, tn);
    __syncthreads();
  }
#pragma unroll
  for (int i = 0; i < 4; ++i) {
    int t = t0 + tm * 4 + i;
    if (t < TDIM)
      *(float4*)(out + (size_t)t * DDIM + d0 + tn * 4) =
          make_float4(acc[i][0], acc[i][1], acc[i][2], acc[i][3]);
  }
}

// ---------------- K5a: h[r][j] = relu(f1[r]. @ Wh_top + TB[r%315])  (NN) ----------------
__global__ void k_h(const float* __restrict__ f1, const float* __restrict__ Wh,
                    const float* __restrict__ TB, float* __restrict__ hbuf) {
  __shared__ float Xs[32 * 72], Ws[32 * 72];
  int tid = threadIdx.x, tm = tid >> 4, tn = tid & 15;
  int h0 = blockIdx.x * 64, r0 = blockIdx.y * 64;
  const int RTOT = BDIM * TDIM;  // 10080
  float acc[4][4] = {};
  for (int k0 = 0; k0 < 512; k0 += 32) {
    stage_T(Xs, f1, r0, 512, k0, tid, RTOT);
    stage_N(Ws, Wh, k0, 256, h0, tid, 512);
    __syncthreads();
    mm_inner(Xs, Ws, acc, tm, tn);
    __syncthreads();
  }
#pragma unroll
  for (int i = 0; i < 4; ++i) {
    int r = r0 + tm * 4 + i;
    if (r < RTOT) {
      int t = r % TDIM;
      int h = h0 + tn * 4;
      float4 v;
      v.x = fmaxf(acc[i][0] + TB[(size_t)t * 256 + h + 0], 0.f);
      v.y = fmaxf(acc[i][1] + TB[(size_t)t * 256 + h + 1], 0.f);
      v.z = fmaxf(acc[i][2] + TB[(size_t)t * 256 + h + 2], 0.f);
      v.w = fmaxf(acc[i][3] + TB[(size_t)t * 256 + h + 3], 0.f);
      *(float4*)(hbuf + (size_t)r * 256 + h) = v;
    }
  }
}

// ---------------- K5b: pred[r] = h[r]. @ Wo + bo ----------------
__global__ void k_pred(const float* __restrict__ hbuf, const float* __restrict__ Wo,
                       const float* __restrict__ bo, float* __restrict__ out) {
  int tid = threadIdx.x;
  int wv = tid >> 6, l = tid & 63;
  int r = blockIdx.x * 4 + wv;
  float s = 0.f;
#pragma unroll
  for (int k = 0; k < 4; ++k)
    s = fmaf(hbuf[(size_t)r * 256 + 64 * k + l], Wo[64 * k + l], s);
#pragma unroll
  for (int m = 1; m <= 32; m <<= 1) s += __shfl_xor(s, m, 64);
  if (l == 0) out[r] = s + bo[0];
}

// ---------------- launch ----------------
extern "C" void kernel_launch(void* const* d_in, const int* in_sizes, int n_in,
                              void* d_out, int out_size, void* d_ws, size_t ws_size,
                              hipStream_t stream) {
  const float* F     = (const float*)d_in[0];
  const float* text  = (const float*)d_in[1];
  const float* A     = (const float*)d_in[2];
  const float* gamma = (const float*)d_in[3];
  const float* beta  = (const float*)d_in[4];
  const float* Wh    = (const float*)d_in[5];
  const float* bh    = (const float*)d_in[6];
  const float* Wo    = (const float*)d_in[7];
  const float* bo    = (const float*)d_in[8];
  float* out = (float*)d_out;
  char* ws = (char*)d_ws;
  float* tA    = (float*)(ws + OFS_TA);
  float* TB    = (float*)(ws + OFS_TB);
  float* stats = (float*)(ws + OFS_STATS);
  float* sbuf  = (float*)(ws + OFS_S);
  float* f1    = (float*)(ws + OFS_F1);
  float* hbuf  = (float*)(ws + OFS_H);

  hipMemsetAsync(stats, 0, BDIM * 2 * sizeof(float), stream);
  k_tA<<<dim3(8, 5), 256, 0, stream>>>(text, A, tA);
  k_TB<<<dim3(4, 5), 256, 0, stream>>>(text, Wh, bh, TB);
  k_s<<<dim3(5, 7, 32), 256, 0, stream>>>(F, tA, sbuf, stats);
  k_sinkhorn<<<dim3(32), 512, 0, stream>>>(sbuf, stats, gamma, beta);
  k_f1<<<dim3(8, 5, 32), 256, 0, stream>>>(sbuf, F, f1);
  k_h<<<dim3(4, 158), 256, 0, stream>>>(f1, Wh, TB, hbuf);
  k_pred<<<dim3(2520), 256, 0, stream>>>(hbuf, Wo, bo, out);
}

// Round 7
// 1435.863 us; speedup vs baseline: 1.4312x; 1.4312x over previous
//
#include <hip/hip_runtime.h>

// Problem dims
#define BDIM 32
#define NDIM 400
#define TDIM 315
#define TPAD 320
#define DDIM 512
#define HDIM 256
#define NITER 100

// Workspace layout (bytes)
#define OFS_TA    0u          // tA[320][512] f32 = 655360
#define OFS_TB    1048576u    // TB[320][256] f32 = 327680   (text @ Wh_bot + bh)
#define OFS_STATS 1572864u    // stats[32][2] f32 = 256      (sum, sumsq per batch)
#define OFS_S     2097152u    // s/s1[32][400][320] f32 = 16384000
#define OFS_F1    18874368u   // f1[32][315][512] f32 = 20643840
#define OFS_H     41943040u   // h[10080][256] f32 = 10321920

// ---------------- shared GEMM pieces: 64x64 tile, BK=32, 256 thr, 4x4 micro ----------------

__device__ __forceinline__ void mm_inner(const float* __restrict__ As, const float* __restrict__ Bs,
                                         float acc[4][4], int tm, int tn) {
#pragma unroll
  for (int k = 0; k < 32; ++k) {
    float4 a = *(const float4*)(As + k * 72 + tm * 4);
    float4 b = *(const float4*)(Bs + k * 72 + tn * 4);
    float ar[4] = {a.x, a.y, a.z, a.w};
    float br[4] = {b.x, b.y, b.z, b.w};
#pragma unroll
    for (int i = 0; i < 4; ++i)
#pragma unroll
      for (int j = 0; j < 4; ++j)
        acc[i][j] = fmaf(ar[i], br[j], acc[i][j]);
  }
}

// Stage X[row][k] (K-contiguous rows) transposed into Xs[k][m]; rows >= rmax -> 0
__device__ __forceinline__ void stage_T(float* __restrict__ Xs, const float* __restrict__ X,
                                        int r0, int ld, int k0, int tid, int rmax) {
  int kq = tid & 7;   // float4 group along K
  int mb = tid >> 3;  // 0..31
#pragma unroll
  for (int p = 0; p < 2; ++p) {
    int mm = mb + 32 * p;
    int row = r0 + mm;
    float4 v = make_float4(0.f, 0.f, 0.f, 0.f);
    if (row < rmax) v = *(const float4*)(X + (size_t)row * ld + k0 + 4 * kq);
    Xs[(4 * kq + 0) * 72 + mm] = v.x;
    Xs[(4 * kq + 1) * 72 + mm] = v.y;
    Xs[(4 * kq + 2) * 72 + mm] = v.z;
    Xs[(4 * kq + 3) * 72 + mm] = v.w;
  }
}

// Stage W[k][n] (N-contiguous rows) into Ws[k][j]; k0+k >= kmax -> 0
__device__ __forceinline__ void stage_N(float* __restrict__ Ws, const float* __restrict__ W,
                                        int k0, int ld, int n0, int tid, int kmax) {
  int nq = tid & 15;
  int kk = tid >> 4;  // 0..15
#pragma unroll
  for (int p = 0; p < 2; ++p) {
    int k = kk + 16 * p;
    float4 v = make_float4(0.f, 0.f, 0.f, 0.f);
    if (k0 + k < kmax) v = *(const float4*)(W + (size_t)(k0 + k) * ld + n0 + 4 * nq);
    *(float4*)(Ws + k * 72 + 4 * nq) = v;
  }
}

// ---------------- K1a: tA[t][d] = sum_e text[t][e] * A[d][e]  (NT) ----------------
__global__ void k_tA(const float* __restrict__ text, const float* __restrict__ A,
                     float* __restrict__ tA) {
  __shared__ float Xs[32 * 72], Ys[32 * 72];
  int tid = threadIdx.x, tm = tid >> 4, tn = tid & 15;
  int d0 = blockIdx.x * 64, t0 = blockIdx.y * 64;
  float acc[4][4] = {};
  for (int k0 = 0; k0 < 512; k0 += 32) {
    stage_T(Xs, text, t0, 512, k0, tid, TDIM);
    stage_T(Ys, A, d0, 512, k0, tid, 512);
    __syncthreads();
    mm_inner(Xs, Ys, acc, tm, tn);
    __syncthreads();
  }
#pragma unroll
  for (int i = 0; i < 4; ++i) {
    int t = t0 + tm * 4 + i;  // pad rows get zeros (Xs zero-filled)
    *(float4*)(tA + (size_t)t * 512 + d0 + tn * 4) =
        make_float4(acc[i][0], acc[i][1], acc[i][2], acc[i][3]);
  }
}

// ---------------- K1b: TB[t][h] = text[t]. @ Wh_bot + bh  (NN) ----------------
__global__ void k_TB(const float* __restrict__ text, const float* __restrict__ Wh,
                     const float* __restrict__ bh, float* __restrict__ TB) {
  __shared__ float Xs[32 * 72], Ws[32 * 72];
  int tid = threadIdx.x, tm = tid >> 4, tn = tid & 15;
  int h0 = blockIdx.x * 64, t0 = blockIdx.y * 64;
  const float* Wb = Wh + 512 * 256;  // bottom half rows of Wh[1024][256]
  float acc[4][4] = {};
  for (int k0 = 0; k0 < 512; k0 += 32) {
    stage_T(Xs, text, t0, 512, k0, tid, TDIM);
    stage_N(Ws, Wb, k0, 256, h0, tid, 512);
    __syncthreads();
    mm_inner(Xs, Ws, acc, tm, tn);
    __syncthreads();
  }
#pragma unroll
  for (int i = 0; i < 4; ++i) {
    int t = t0 + tm * 4 + i;
    int h = h0 + tn * 4;
    *(float4*)(TB + (size_t)t * 256 + h) =
        make_float4(acc[i][0] + bh[h], acc[i][1] + bh[h + 1],
                    acc[i][2] + bh[h + 2], acc[i][3] + bh[h + 3]);
  }
}

// ---------------- K2: s[b][n][t] = F[b][n]. dot tA[t].  (NT) + instnorm stats ----------------
__global__ void k_s(const float* __restrict__ F, const float* __restrict__ tA,
                    float* __restrict__ s, float* __restrict__ stats) {
  __shared__ float Xs[32 * 72], Ys[32 * 72];
  __shared__ float red[8];
  int tid = threadIdx.x, tm = tid >> 4, tn = tid & 15;
  int t0 = blockIdx.x * 64, n0 = blockIdx.y * 64, bz = blockIdx.z;
  const float* Fb = F + (size_t)bz * NDIM * DDIM;
  float* sb = s + (size_t)bz * NDIM * TPAD;
  float acc[4][4] = {};
  for (int k0 = 0; k0 < 512; k0 += 32) {
    stage_T(Xs, Fb, n0, 512, k0, tid, NDIM);
    stage_T(Ys, tA, t0, 512, k0, tid, TPAD);  // pad rows of tA are zeros
    __syncthreads();
    mm_inner(Xs, Ys, acc, tm, tn);
    __syncthreads();
  }
  float lsum = 0.f, lsq = 0.f;
#pragma unroll
  for (int i = 0; i < 4; ++i) {
    int n = n0 + tm * 4 + i;
    if (n < NDIM) {
      int tb = t0 + tn * 4;
      if (tb + 3 < TDIM) {
        *(float4*)(sb + (size_t)n * TPAD + tb) =
            make_float4(acc[i][0], acc[i][1], acc[i][2], acc[i][3]);
#pragma unroll
        for (int j = 0; j < 4; ++j) { lsum += acc[i][j]; lsq = fmaf(acc[i][j], acc[i][j], lsq); }
      } else {
#pragma unroll
        for (int j = 0; j < 4; ++j) {
          int t = tb + j;
          if (t < TDIM) {
            sb[(size_t)n * TPAD + t] = acc[i][j];
            lsum += acc[i][j]; lsq = fmaf(acc[i][j], acc[i][j], lsq);
          }
        }
      }
    }
  }
#pragma unroll
  for (int m = 1; m <= 32; m <<= 1) {
    lsum += __shfl_xor(lsum, m, 64);
    lsq  += __shfl_xor(lsq, m, 64);
  }
  int wv = tid >> 6;
  if ((tid & 63) == 0) { red[wv * 2] = lsum; red[wv * 2 + 1] = lsq; }
  __syncthreads();
  if (tid == 0) {
    float S = red[0] + red[2] + red[4] + red[6];
    float Q = red[1] + red[3] + red[5] + red[7];
    atomicAdd(&stats[bz * 2], S);
    atomicAdd(&stats[bz * 2 + 1], Q);
  }
}

// ---------------- DPP wave-64 sum helpers (VALU pipe, no LDS) ----------------
template <int CTRL, int RMASK>
__device__ __forceinline__ float dppadd(float x) {
  int y = __builtin_amdgcn_update_dpp(0, __float_as_int(x), CTRL, RMASK, 0xf, true);
  return x + __int_as_float(y);
}

// ---------------- bf16 pack/unpack (RNE) ----------------
__device__ __forceinline__ unsigned rne_hi(float x) {
  unsigned u = __float_as_uint(x);
  u += 0x7fffu + ((u >> 16) & 1u);
  return u & 0xffff0000u;
}
__device__ __forceinline__ unsigned pack2(float lo, float hi) {
  return (rne_hi(lo) >> 16) | rne_hi(hi);
}
__device__ __forceinline__ float unpk_lo(unsigned p) { return __uint_as_float(p << 16); }
__device__ __forceinline__ float unpk_hi(unsigned p) { return __uint_as_float(p & 0xffff0000u); }

// ---------------- K3: fused instnorm finalize + 100-iter sinkhorn (matrix scaling) ----------------
// 512 threads (8 waves). R3-R6 measured: the allocator pins VGPRs at 128 for 512-thr blocks no
// matter what (__launch_bounds__ 2nd arg, waves_per_eu, bf16-packed 100-reg arrays all failed —
// live state ~130-140 still spilled). This round: leave REAL headroom. E stripes 0-1 in registers
// as 50 bf16-packed uints (50 VGPRs); stripes 2-3 in LDS bf16-packed (102.4 KB); stripe 4 in LDS
// bf16 ushorts (51.2 KB). qacc replaced by ds_add_f32 atomics into qsum[320]. Peak live ~95 VGPRs.
// Iterate a = 1/(E w), w = 1/(E^T a); output s1 = a_100 * E * w_100 with a_100 saved in the peeled
// LAST iteration only — reference ends on a COL normalization; recomputing a would add a row norm.
__global__ __launch_bounds__(512) void k_sinkhorn(float* __restrict__ sbuf,
                                                  const float* __restrict__ stats,
                                                  const float* __restrict__ gptr,
                                                  const float* __restrict__ bptr) {
  __shared__ unsigned Epk23[400 * 64];       // (stripe2, stripe3) bf16-packed   = 102400 B
  __shared__ unsigned short Eu4[400 * 64];   // stripe 4 bf16 (0 for pad cols)   =  51200 B
  __shared__ float wl[320];                  // col scaling w[t] (0 for t>=315)  =   1280 B
  __shared__ float qsum[320];                // atomic col accumulator           =   1280 B
  __shared__ float albuf[400];               // a[n] from the final row step     =   1600 B
  const int b = blockIdx.x;
  const int tid = threadIdx.x;
  const int wv = tid >> 6;           // 0..7
  const int l = tid & 63;
  float* S = sbuf + (size_t)b * NDIM * TPAD;
  const float NT = 400.0f * 315.0f;
  const float mean = stats[2 * b] / NT;
  const float var = stats[2 * b + 1] / NT - mean * mean;
  const float inv = rsqrtf(var + 1e-5f);
  const float gamma = gptr[0], beta = bptr[0];
  const float alpha = gamma * inv;
  const float L2E = 1.4426950408889634f;
  const float a2 = alpha * L2E;
  const float d2 = (beta - mean * alpha) * L2E;
  const int nbase = wv * 50;         // 50 rows per wave

  unsigned E01[50];                  // (stripe0, stripe1) bf16-packed, registers
#pragma unroll
  for (int j = 0; j < 50; ++j) {
    const float* row = S + (size_t)(nbase + j) * TPAD;
    float e0 = __builtin_amdgcn_exp2f(fmaf(row[l], a2, d2));
    float e1 = __builtin_amdgcn_exp2f(fmaf(row[64 + l], a2, d2));
    float e2 = __builtin_amdgcn_exp2f(fmaf(row[128 + l], a2, d2));
    float e3 = __builtin_amdgcn_exp2f(fmaf(row[192 + l], a2, d2));
    E01[j] = pack2(e0, e1);
    Epk23[(nbase + j) * 64 + l] = pack2(e2, e3);
    float e4 = 0.0f;
    if (l < 59) e4 = __builtin_amdgcn_exp2f(fmaf(row[256 + l], a2, d2));
    Eu4[(nbase + j) * 64 + l] = (unsigned short)(rne_hi(e4) >> 16);
  }
  if (tid < 320) { wl[tid] = (tid < 315) ? 1.0f : 0.0f; qsum[tid] = 0.0f; }
  __syncthreads();

  for (int it = 0; it < NITER; ++it) {
    const bool last = (it == NITER - 1);
    float w0 = wl[l], w1 = wl[64 + l], w2 = wl[128 + l], w3 = wl[192 + l], w4 = wl[256 + l];
    float q0 = 0.f, q1 = 0.f, q2 = 0.f, q3 = 0.f, q4 = 0.f;
#pragma unroll
    for (int jc = 0; jc < 10; ++jc) {
      float p[5], e2v[5], e3v[5], e4v[5];
#pragma unroll
      for (int u = 0; u < 5; ++u) {
        const int j = jc * 5 + u;
        unsigned v23 = Epk23[(nbase + j) * 64 + l];
        e2v[u] = unpk_lo(v23);
        e3v[u] = unpk_hi(v23);
        e4v[u] = __uint_as_float(((unsigned)Eu4[(nbase + j) * 64 + l]) << 16);
        float t = e4v[u] * w4;
        t = fmaf(e3v[u], w3, t);
        t = fmaf(e2v[u], w2, t);
        t = fmaf(unpk_hi(E01[j]), w1, t);
        p[u] = fmaf(unpk_lo(E01[j]), w0, t);
      }
      // 5 interleaved DPP reduction chains (ILP), results uniform in SGPRs
      float aj[5];
#pragma unroll
      for (int u = 0; u < 5; ++u) p[u] = dppadd<0x111, 0xf>(p[u]);
#pragma unroll
      for (int u = 0; u < 5; ++u) p[u] = dppadd<0x112, 0xf>(p[u]);
#pragma unroll
      for (int u = 0; u < 5; ++u) p[u] = dppadd<0x114, 0xf>(p[u]);
#pragma unroll
      for (int u = 0; u < 5; ++u) p[u] = dppadd<0x118, 0xf>(p[u]);
#pragma unroll
      for (int u = 0; u < 5; ++u) p[u] = dppadd<0x142, 0xa>(p[u]);
#pragma unroll
      for (int u = 0; u < 5; ++u) p[u] = dppadd<0x143, 0xc>(p[u]);
#pragma unroll
      for (int u = 0; u < 5; ++u) {
        float r = __builtin_amdgcn_rcpf(p[u]);
        aj[u] = __int_as_float(__builtin_amdgcn_readlane(__float_as_int(r), 63));
      }
#pragma unroll
      for (int u = 0; u < 5; ++u) {
        const int j = jc * 5 + u;
        q0 = fmaf(unpk_lo(E01[j]), aj[u], q0);
        q1 = fmaf(unpk_hi(E01[j]), aj[u], q1);
        q2 = fmaf(e2v[u], aj[u], q2);
        q3 = fmaf(e3v[u], aj[u], q3);
        q4 = fmaf(e4v[u], aj[u], q4);
      }
      if (last && l == 0) {
#pragma unroll
        for (int u = 0; u < 5; ++u) albuf[nbase + jc * 5 + u] = aj[u];
      }
    }
    atomicAdd(&qsum[l], q0);
    atomicAdd(&qsum[64 + l], q1);
    atomicAdd(&qsum[128 + l], q2);
    atomicAdd(&qsum[192 + l], q3);
    atomicAdd(&qsum[256 + l], q4);
    __syncthreads();
    if (tid < 320) {
      float q = qsum[tid];
      wl[tid] = (tid < 315) ? __builtin_amdgcn_rcpf(q) : 0.0f;
      qsum[tid] = 0.0f;  // re-zero for next iteration
    }
    __syncthreads();
  }

  // epilogue: s1 = a_100 * E * w_100 (a from albuf — NO extra row normalization)
  {
    float w0 = wl[l], w1 = wl[64 + l], w2 = wl[128 + l], w3 = wl[192 + l], w4 = wl[256 + l];
#pragma unroll
    for (int j = 0; j < 50; ++j) {
      const float aj = albuf[nbase + j];
      unsigned v23 = Epk23[(nbase + j) * 64 + l];
      float e4 = __uint_as_float(((unsigned)Eu4[(nbase + j) * 64 + l]) << 16);
      float* row = S + (size_t)(nbase + j) * TPAD;
      row[l] = aj * unpk_lo(E01[j]) * w0;
      row[64 + l] = aj * unpk_hi(E01[j]) * w1;
      row[128 + l] = aj * unpk_lo(v23) * w2;
      row[192 + l] = aj * unpk_hi(v23) * w3;
      if (l < 59) row[256 + l] = aj * e4 * w4;
    }
  }
}

// ---------------- K4: f1[b][t][d] = sum_n s1[b][n][t] * F[b][n][d]  (TN) ----------------
__global__ void k_f1(const float* __restrict__ s1, const float* __restrict__ F,
                     float* __restrict__ f1) {
  __shared__ float Xs[32 * 72], Ws[32 * 72];
  int tid = threadIdx.x, tm = tid >> 4, tn = tid & 15;
  int d0 = blockIdx.x * 64, t0 = blockIdx.y * 64, bz = blockIdx.z;
  const float* sb = s1 + (size_t)bz * NDIM * TPAD;
  const float* Fb = F + (size_t)bz * NDIM * DDIM;
  float* out = f1 + (size_t)bz * TDIM * DDIM;
  float acc[4][4] = {};
  for (int k0 = 0; k0 < 416; k0 += 32) {  // 13 chunks cover K=400 (masked)
    stage_N(Xs, sb, k0, TPAD, t0, tid, NDIM);
    stage_N(Ws, Fb, k0, DDIM, d0, tid, NDIM);
    __syncthreads();
    mm_inner(Xs, Ws, acc, tm, tn);
    __syncthreads();
  }
#pragma unroll
  for (int i = 0; i < 4; ++i) {
    int t = t0 + tm * 4 + i;
    if (t < TDIM)
      *(float4*)(out + (size_t)t * DDIM + d0 + tn * 4) =
          make_float4(acc[i][0], acc[i][1], acc[i][2], acc[i][3]);
  }
}

// ---------------- K5a: h[r][j] = relu(f1[r]. @ Wh_top + TB[r%315])  (NN) ----------------
__global__ void k_h(const float* __restrict__ f1, const float* __restrict__ Wh,
                    const float* __restrict__ TB, float* __restrict__ hbuf) {
  __shared__ float Xs[32 * 72], Ws[32 * 72];
  int tid = threadIdx.x, tm = tid >> 4, tn = tid & 15;
  int h0 = blockIdx.x * 64, r0 = blockIdx.y * 64;
  const int RTOT = BDIM * TDIM;  // 10080
  float acc[4][4] = {};
  for (int k0 = 0; k0 < 512; k0 += 32) {
    stage_T(Xs, f1, r0, 512, k0, tid, RTOT);
    stage_N(Ws, Wh, k0, 256, h0, tid, 512);
    __syncthreads();
    mm_inner(Xs, Ws, acc, tm, tn);
    __syncthreads();
  }
#pragma unroll
  for (int i = 0; i < 4; ++i) {
    int r = r0 + tm * 4 + i;
    if (r < RTOT) {
      int t = r % TDIM;
      int h = h0 + tn * 4;
      float4 v;
      v.x = fmaxf(acc[i][0] + TB[(size_t)t * 256 + h + 0], 0.f);
      v.y = fmaxf(acc[i][1] + TB[(size_t)t * 256 + h + 1], 0.f);
      v.z = fmaxf(acc[i][2] + TB[(size_t)t * 256 + h + 2], 0.f);
      v.w = fmaxf(acc[i][3] + TB[(size_t)t * 256 + h + 3], 0.f);
      *(float4*)(hbuf + (size_t)r * 256 + h) = v;
    }
  }
}

// ---------------- K5b: pred[r] = h[r]. @ Wo + bo ----------------
__global__ void k_pred(const float* __restrict__ hbuf, const float* __restrict__ Wo,
                       const float* __restrict__ bo, float* __restrict__ out) {
  int tid = threadIdx.x;
  int wv = tid >> 6, l = tid & 63;
  int r = blockIdx.x * 4 + wv;
  float s = 0.f;
#pragma unroll
  for (int k = 0; k < 4; ++k)
    s = fmaf(hbuf[(size_t)r * 256 + 64 * k + l], Wo[64 * k + l], s);
#pragma unroll
  for (int m = 1; m <= 32; m <<= 1) s += __shfl_xor(s, m, 64);
  if (l == 0) out[r] = s + bo[0];
}

// ---------------- launch ----------------
extern "C" void kernel_launch(void* const* d_in, const int* in_sizes, int n_in,
                              void* d_out, int out_size, void* d_ws, size_t ws_size,
                              hipStream_t stream) {
  const float* F     = (const float*)d_in[0];
  const float* text  = (const float*)d_in[1];
  const float* A     = (const float*)d_in[2];
  const float* gamma = (const float*)d_in[3];
  const float* beta  = (const float*)d_in[4];
  const float* Wh    = (const float*)d_in[5];
  const float* bh    = (const float*)d_in[6];
  const float* Wo    = (const float*)d_in[7];
  const float* bo    = (const float*)d_in[8];
  float* out = (float*)d_out;
  char* ws = (char*)d_ws;
  float* tA    = (float*)(ws + OFS_TA);
  float* TB    = (float*)(ws + OFS_TB);
  float* stats = (float*)(ws + OFS_STATS);
  float* sbuf  = (float*)(ws + OFS_S);
  float* f1    = (float*)(ws + OFS_F1);
  float* hbuf  = (float*)(ws + OFS_H);

  hipMemsetAsync(stats, 0, BDIM * 2 * sizeof(float), stream);
  k_tA<<<dim3(8, 5), 256, 0, stream>>>(text, A, tA);
  k_TB<<<dim3(4, 5), 256, 0, stream>>>(text, Wh, bh, TB);
  k_s<<<dim3(5, 7, 32), 256, 0, stream>>>(F, tA, sbuf, stats);
  k_sinkhorn<<<dim3(32), 512, 0, stream>>>(sbuf, stats, gamma, beta);
  k_f1<<<dim3(8, 5, 32), 256, 0, stream>>>(sbuf, F, f1);
  k_h<<<dim3(4, 158), 256, 0, stream>>>(f1, Wh, TB, hbuf);
  k_pred<<<dim3(2520), 256, 0, stream>>>(hbuf, Wo, bo, out);
}